// Round 4
// baseline (943.398 us; speedup 1.0000x reference)
//
#include <hip/hip_runtime.h>
#include <hip/hip_cooperative_groups.h>

namespace cg = cooperative_groups;

typedef __bf16 bf16;
typedef __bf16 bf16x8 __attribute__((ext_vector_type(8)));
typedef __bf16 bf16x4 __attribute__((ext_vector_type(4)));
typedef float f32x4 __attribute__((ext_vector_type(4)));

#define LCTX 512
#define HD 1024

struct KArgs {
    const float* x; const float* lq; const unsigned char* mask; const float* qe;
    const float* W1; const float* b1; const float* W2;
    const float* W3; const float* b3; const float* Wc; const float* bc;
    const float* gc; const float* betac;
    const float* Wf1; const float* bf1; const float* gf1; const float* betaf1;
    const float* Wf2; const float* bf2; const float* gf2; const float* betaf2;
    bf16* W3t; bf16* Wct; bf16* Wf1t; bf16* Wf2t; bf16* X;
    float* kpartial; float* kbuf; float* mbuf; float* attb; float* pbuf;
    bf16* ybuf; bf16* ctxp; float* Cbuf; bf16* t1;
    float* out;
};

__device__ __forceinline__ float wave_sum(float v) {
    for (int off = 32; off; off >>= 1) v += __shfl_xor(v, off, 64);
    return v;
}
__device__ __forceinline__ float wave_max(float v) {
    for (int off = 32; off; off >>= 1) v = fmaxf(v, __shfl_xor(v, off, 64));
    return v;
}

__device__ __forceinline__ void gl16(const bf16* g, bf16* l) {
    __builtin_amdgcn_global_load_lds((const __attribute__((address_space(1))) void*)g,
                                     (__attribute__((address_space(3))) void*)l, 16, 0, 0);
}
__device__ __forceinline__ bf16x8 ldsfrag(const bf16* base, int row, int kb) {
    // logical (row,kb) -> phys col (kb ^ (row&7)); 16B granules, row stride 64 bf16
    return *(const bf16x8*)(base + row * 64 + ((kb ^ (row & 7)) << 3));
}

// MFMA GEMM phase: C[1024,N=1024] = A[.,K] @ Bt[N,K]^T + bias; 256 x (64x64) tiles
__device__ void gemm_phase(const bf16* A, int lda, const bf16* Bt, int ldb,
                           const float* bias, void* Cv, int ldc, int K, int outbf,
                           char* smem) {
    bf16* sA = (bf16*)smem;             // [2][4096] bf16
    bf16* sB = (bf16*)(smem + 16384);   // [2][4096] bf16
    int tid = threadIdx.x;
    int wave = tid >> 6, lane = tid & 63;
    int l16 = lane & 15, lhi = lane >> 4;
    int wr = (wave >> 1) * 32, wc = (wave & 1) * 32;
    int r0 = tid >> 3, kb = tid & 7;
    int r1 = r0 + 32;
    int sk0 = (kb ^ (r0 & 7)) << 3;     // pre-swizzled source column (bf16 elems)
    int sk1 = (kb ^ (r1 & 7)) << 3;
    int wb0 = wave * 512;               // wave-uniform LDS chunk base (bf16 elems)
    int wb1 = 2048 + wave * 512;
    for (int vb = blockIdx.x; vb < 256; vb += gridDim.x) {
        int m0 = (vb & 15) * 64, n0 = (vb >> 4) * 64;
        const bf16* A0 = A + (size_t)(m0 + r0) * lda + sk0;
        const bf16* A1 = A + (size_t)(m0 + r1) * lda + sk1;
        const bf16* B0 = Bt + (size_t)(n0 + r0) * ldb + sk0;
        const bf16* B1 = Bt + (size_t)(n0 + r1) * ldb + sk1;
        f32x4 acc00 = {}, acc01 = {}, acc10 = {}, acc11 = {};
        int nt = K >> 6;
        __syncthreads();                 // LDS reuse guard across vb iters
        gl16(A0, &sA[wb0]); gl16(A1, &sA[wb1]);
        gl16(B0, &sB[wb0]); gl16(B1, &sB[wb1]);
        asm volatile("s_waitcnt vmcnt(0)" ::: "memory");
        __syncthreads();
        int cur = 0;
        for (int tI = 0; tI < nt; ++tI) {
            if (tI + 1 < nt) {
                int ko = (tI + 1) << 6;
                gl16(A0 + ko, &sA[(cur ^ 1) * 4096 + wb0]);
                gl16(A1 + ko, &sA[(cur ^ 1) * 4096 + wb1]);
                gl16(B0 + ko, &sB[(cur ^ 1) * 4096 + wb0]);
                gl16(B1 + ko, &sB[(cur ^ 1) * 4096 + wb1]);
            }
            const bf16* a = sA + cur * 4096;
            const bf16* bt = sB + cur * 4096;
#pragma unroll
            for (int ks = 0; ks < 2; ks++) {
                int kbb = ks * 4 + lhi;
                bf16x8 a0 = ldsfrag(a, wr + l16, kbb);
                bf16x8 a1v = ldsfrag(a, wr + 16 + l16, kbb);
                bf16x8 b0v = ldsfrag(bt, wc + l16, kbb);
                bf16x8 b1v = ldsfrag(bt, wc + 16 + l16, kbb);
                acc00 = __builtin_amdgcn_mfma_f32_16x16x32_bf16(a0, b0v, acc00, 0, 0, 0);
                acc01 = __builtin_amdgcn_mfma_f32_16x16x32_bf16(a0, b1v, acc01, 0, 0, 0);
                acc10 = __builtin_amdgcn_mfma_f32_16x16x32_bf16(a1v, b0v, acc10, 0, 0, 0);
                acc11 = __builtin_amdgcn_mfma_f32_16x16x32_bf16(a1v, b1v, acc11, 0, 0, 0);
            }
            asm volatile("s_waitcnt vmcnt(0)" ::: "memory");
            __syncthreads();
            cur ^= 1;
        }
        f32x4 accs[2][2] = {{acc00, acc01}, {acc10, acc11}};
#pragma unroll
        for (int mi = 0; mi < 2; mi++)
#pragma unroll
            for (int ni = 0; ni < 2; ni++)
#pragma unroll
                for (int r = 0; r < 4; r++) {
                    int row = m0 + wr + mi * 16 + lhi * 4 + r;
                    int col = n0 + wc + ni * 16 + l16;
                    float v = accs[mi][ni][r] + bias[col];
                    if (outbf)
                        ((bf16*)Cv)[(size_t)row * ldc + col] = (bf16)v;
                    else
                        ((float*)Cv)[(size_t)row * ldc + col] = v;
                }
    }
}

// LayerNorm of one 1024-row of C; returns per-thread float4 (cols t*4..t*4+3)
__device__ __forceinline__ float4 ln_row(const float* C, const float* g, const float* beta,
                                         int row, int t, float* red) {
    float4 v = ((const float4*)(C + (size_t)row * 1024))[t];
    float s = v.x + v.y + v.z + v.w;
    float s2 = v.x * v.x + v.y * v.y + v.z * v.z + v.w * v.w;
    s = wave_sum(s); s2 = wave_sum(s2);
    int wave = t >> 6, lane = t & 63;
    if (lane == 0) { red[wave] = s; red[4 + wave] = s2; }
    __syncthreads();
    float S = red[0] + red[1] + red[2] + red[3];
    float S2 = red[4] + red[5] + red[6] + red[7];
    float mean = S * (1.f / 1024.f);
    float var = S2 * (1.f / 1024.f) - mean * mean;
    float inv = rsqrtf(var + 1e-5f);
    float4 gv = ((const float4*)g)[t];
    float4 bv = ((const float4*)beta)[t];
    float4 o;
    o.x = (v.x - mean) * inv * gv.x + bv.x;
    o.y = (v.y - mean) * inv * gv.y + bv.y;
    o.z = (v.z - mean) * inv * gv.z + bv.z;
    o.w = (v.w - mean) * inv * gv.w + bv.w;
    return o;
}

__global__ __launch_bounds__(256, 4) void mega_kernel(KArgs a) {
    cg::grid_group grid = cg::this_grid();
    __shared__ __align__(16) char smem[33792];
    int t = threadIdx.x;
    int nb = gridDim.x;
    int wave = t >> 6, lane = t & 63;

    // ============ P0: prep (weight transposes + lqconv) + kpart =============
    {
        float (*tile)[33] = (float(*)[33])smem;
        float (*xs)[68] = (float(*)[68])smem;                 // kpart A
        float (*wsm)[64] = (float(*)[64])(smem + 17408);      // kpart B
        for (int vb = blockIdx.x; vb < 6400; vb += nb) {
            __syncthreads();
            if (vb < 5120) {
                const float* W; bf16* Wt; int K, N, i;
                if (vb < 1024)      { W = a.W3;  Wt = a.W3t;  K = 1024; N = 1024; i = vb; }
                else if (vb < 2048) { W = a.Wc;  Wt = a.Wct;  K = 1024; N = 1024; i = vb - 1024; }
                else if (vb < 3072) { W = a.Wf2; Wt = a.Wf2t; K = 1024; N = 1024; i = vb - 2048; }
                else                { W = a.Wf1; Wt = a.Wf1t; K = 2048; N = 1024; i = vb - 3072; }
                int k0 = (i >> 5) * 32, n0 = (i & 31) * 32;
                int c = t & 31, r = t >> 5;
#pragma unroll
                for (int j = 0; j < 4; j++)
                    tile[r + j * 8][c] = W[(size_t)(k0 + r + j * 8) * N + n0 + c];
                __syncthreads();
#pragma unroll
                for (int j = 0; j < 4; j++)
                    Wt[(size_t)(n0 + r + j * 8) * K + k0 + c] = (bf16)tile[c][r + j * 8];
            } else if (vb < 6144) {
                int i = (vb - 5120) * 256 + t;
                float4 v = ((const float4*)a.lq)[i];
                int row = i >> 8, h4 = i & 255;
                bf16x4 o = {(bf16)v.x, (bf16)v.y, (bf16)v.z, (bf16)v.w};
                *(bf16x4*)(a.X + (size_t)row * 2048 + 1024 + h4 * 4) = o;
            } else {
                int kv = vb - 6144;                      // 0..255
                int n0 = (kv & 15) * 64, k0 = (kv >> 4) * 64;
#pragma unroll
                for (int i = 0; i < 4; i++) {
                    int f = t + i * 256;
                    int b = f >> 4, c = f & 15;
                    *(float4*)&xs[b][c * 4] =
                        *(const float4*)(a.x + (size_t)b * LCTX * HD + k0 + c * 4);
                }
#pragma unroll
                for (int i = 0; i < 4; i++) {
                    int f = t + i * 256;
                    int r = f >> 4, c = f & 15;
                    *(float4*)&wsm[r][c * 4] =
                        *(const float4*)(a.W1 + (size_t)(k0 + r) * 1024 + n0 + c * 4);
                }
                __syncthreads();
                int tb = t >> 4, tc = t & 15;
                int b0 = tb * 4;
                float acc[4][4] = {};
                for (int kk = 0; kk < 64; kk += 4) {
                    float4 w0 = *(const float4*)&wsm[kk + 0][tc * 4];
                    float4 w1 = *(const float4*)&wsm[kk + 1][tc * 4];
                    float4 w2 = *(const float4*)&wsm[kk + 2][tc * 4];
                    float4 w3 = *(const float4*)&wsm[kk + 3][tc * 4];
                    float4 xv[4];
#pragma unroll
                    for (int bi = 0; bi < 4; bi++) xv[bi] = *(const float4*)&xs[b0 + bi][kk];
#pragma unroll
                    for (int bi = 0; bi < 4; bi++) {
                        acc[bi][0] += xv[bi].x * w0.x + xv[bi].y * w1.x + xv[bi].z * w2.x + xv[bi].w * w3.x;
                        acc[bi][1] += xv[bi].x * w0.y + xv[bi].y * w1.y + xv[bi].z * w2.y + xv[bi].w * w3.y;
                        acc[bi][2] += xv[bi].x * w0.z + xv[bi].y * w1.z + xv[bi].z * w2.z + xv[bi].w * w3.z;
                        acc[bi][3] += xv[bi].x * w0.w + xv[bi].y * w1.w + xv[bi].z * w2.w + xv[bi].w * w3.w;
                    }
                }
                float* pout = a.kpartial + ((size_t)(kv >> 4) * 64 + b0) * 1024 + n0 + tc * 4;
#pragma unroll
                for (int bi = 0; bi < 4; bi++)
                    *(float4*)(pout + (size_t)bi * 1024) =
                        make_float4(acc[bi][0], acc[bi][1], acc[bi][2], acc[bi][3]);
            }
        }
    }
    grid.sync();

    // ============ P1: kreduce =============
    for (int vb = blockIdx.x; vb < 64; vb += nb) {
        float4 acc = ((const float4*)a.b1)[t];
#pragma unroll
        for (int kt = 0; kt < 16; kt++) {
            float4 v = ((const float4*)(a.kpartial + ((size_t)kt * 64 + vb) * 1024))[t];
            acc.x += v.x; acc.y += v.y; acc.z += v.z; acc.w += v.w;
        }
        ((float4*)(a.kbuf + (size_t)vb * 1024))[t] = acc;
    }
    grid.sync();

    // ============ P2: mmat  m[b,i] = W2[i,:] . k[b,:] =============
    {
        float* ks = (float*)smem;
        for (int vb = blockIdx.x; vb < 1024; vb += nb) {
            int b = vb >> 4, i0 = (vb & 15) * 64;
            __syncthreads();
            *(float4*)&ks[t * 4] = ((const float4*)(a.kbuf + (size_t)b * 1024))[t];
            __syncthreads();
            for (int rr = 0; rr < 16; rr++) {
                int i = i0 + wave * 16 + rr;
                const float* wrow = a.W2 + (size_t)i * 1024;
                float s = 0.f;
#pragma unroll
                for (int j = 0; j < 4; j++) {
                    float4 wv = ((const float4*)wrow)[lane + j * 64];
                    const float4 kv = *(const float4*)&ks[(lane + j * 64) * 4];
                    s += wv.x * kv.x + wv.y * kv.y + wv.z * kv.z + wv.w * kv.w;
                }
                s = wave_sum(s);
                if (lane == 0) a.mbuf[(size_t)b * 1024 + i] = s;
            }
        }
    }
    grid.sync();

    // ============ P3: att[b,l] = x[b,l,:] . m[b,:] =============
    {
        float* ms = (float*)smem;
        for (int vb = blockIdx.x; vb < 1024; vb += nb) {
            int b = vb >> 4, l0 = (vb & 15) * 32;
            __syncthreads();
            *(float4*)&ms[t * 4] = ((const float4*)(a.mbuf + (size_t)b * 1024))[t];
            __syncthreads();
            for (int rr = 0; rr < 8; rr++) {
                int l = l0 + wave * 8 + rr;
                const float* xr = a.x + ((size_t)b * LCTX + l) * HD;
                float s = 0.f;
#pragma unroll
                for (int j = 0; j < 4; j++) {
                    float4 xv = ((const float4*)xr)[lane + j * 64];
                    const float4 mv = *(const float4*)&ms[(lane + j * 64) * 4];
                    s += xv.x * mv.x + xv.y * mv.y + xv.z * mv.z + xv.w * mv.w;
                }
                s = wave_sum(s);
                if (lane == 0) a.attb[(size_t)b * LCTX + l] = s;
            }
        }
    }
    grid.sync();

    // ============ P4: masked softmax (inline mask-dtype detect) =============
    {
        float* red1 = (float*)smem;
        float* red2 = (float*)(smem + 32);
        int* sstrp = (int*)(smem + 64);
        for (int vb = blockIdx.x; vb < 1024; vb += nb) {
            int b = vb >> 4;
            __syncthreads();
            if (t == 0) *sstrp = 4;
            __syncthreads();
            if (t < 128 && ((const unsigned int*)a.mask)[t] > 1u) *sstrp = 1;
            __syncthreads();
            int stride = *sstrp;
            size_t base = (size_t)vb * LCTX;
            bool mk0 = a.mask[(base + t) * (size_t)stride] != 0;
            bool mk1 = a.mask[(base + t + 256) * (size_t)stride] != 0;
            float a0 = mk0 ? -1e30f : a.attb[(size_t)b * LCTX + t];
            float a1 = mk1 ? -1e30f : a.attb[(size_t)b * LCTX + t + 256];
            float mx = wave_max(fmaxf(a0, a1));
            if (lane == 0) red1[wave] = mx;
            __syncthreads();
            mx = fmaxf(fmaxf(red1[0], red1[1]), fmaxf(red1[2], red1[3]));
            float e0 = mk0 ? 0.f : expf(a0 - mx);
            float e1 = mk1 ? 0.f : expf(a1 - mx);
            float s = wave_sum(e0 + e1);
            if (lane == 0) red2[wave] = s;
            __syncthreads();
            s = red2[0] + red2[1] + red2[2] + red2[3];
            float inv = 1.f / s;
            a.pbuf[base + t] = e0 * inv;
            a.pbuf[base + t + 256] = e1 * inv;
        }
    }
    grid.sync();

    // ============ P5: y[b,pp,c] = sum_l p[b,pp,l] * x[b,l,c] =============
    {
        float (*ps)[512] = (float(*)[512])smem;
        for (int vb = blockIdx.x; vb < 256; vb += nb) {
            int b = vb >> 2, c0 = (vb & 3) * 256;
            __syncthreads();
            {
                const float4* pp = (const float4*)(a.pbuf + (size_t)b * 16 * 512);
                float4* psv = (float4*)ps;
                for (int i = t; i < 2048; i += 256) psv[i] = pp[i];
            }
            __syncthreads();
            float acc[16] = {};
            const float* xb = a.x + (size_t)b * LCTX * HD + c0 + t;
            for (int l = 0; l < 512; l++) {
                float xv = xb[(size_t)l * HD];
#pragma unroll
                for (int q = 0; q < 16; q++) acc[q] += ps[q][l] * xv;
            }
#pragma unroll
            for (int q = 0; q < 16; q++)
                a.ybuf[((size_t)(b * 16 + q)) * HD + c0 + t] = (bf16)acc[q];
        }
    }
    grid.sync();

    // ============ P6..P12: GEMM chain + LN epilogues =============
    gemm_phase(a.ybuf, 1024, a.W3t, 1024, a.b3, a.ctxp, 1024, 1024, 1, smem);
    grid.sync();
    gemm_phase(a.ctxp, 1024, a.Wct, 1024, a.bc, a.Cbuf, 1024, 1024, 0, smem);
    grid.sync();
    {   // ln0: X[row][0..1024) = bf16( LN(Cbuf)*gc+betac + x0[b] )
        float* red = (float*)smem;
        for (int vb = blockIdx.x; vb < 1024; vb += nb) {
            __syncthreads();
            float4 o = ln_row(a.Cbuf, a.gc, a.betac, vb, t, red);
            int b = vb >> 4;
            const float* x0 = a.x + (size_t)b * LCTX * HD + t * 4;
            bf16x4 w = {(bf16)(o.x + x0[0]), (bf16)(o.y + x0[1]),
                        (bf16)(o.z + x0[2]), (bf16)(o.w + x0[3])};
            *(bf16x4*)(a.X + (size_t)vb * 2048 + t * 4) = w;
        }
    }
    grid.sync();
    gemm_phase(a.X, 2048, a.Wf1t, 2048, a.bf1, a.Cbuf, 1024, 2048, 0, smem);
    grid.sync();
    {   // ln1: t1 = bf16(relu(LN(Cbuf)*gf1+betaf1))
        float* red = (float*)smem;
        for (int vb = blockIdx.x; vb < 1024; vb += nb) {
            __syncthreads();
            float4 o = ln_row(a.Cbuf, a.gf1, a.betaf1, vb, t, red);
            bf16x4 w = {(bf16)fmaxf(o.x, 0.f), (bf16)fmaxf(o.y, 0.f),
                        (bf16)fmaxf(o.z, 0.f), (bf16)fmaxf(o.w, 0.f)};
            *(bf16x4*)(a.t1 + (size_t)vb * 1024 + t * 4) = w;
        }
    }
    grid.sync();
    gemm_phase(a.t1, 1024, a.Wf2t, 1024, a.bf2, a.Cbuf, 1024, 1024, 0, smem);
    grid.sync();
    {   // lnout: relu(LN) then tile + query_embed -> both output halves
        float* red = (float*)smem;
        float* out0 = a.out;
        float* out1 = a.out + (size_t)256 * 64 * 1024;
        for (int vb = blockIdx.x; vb < 1024; vb += nb) {
            __syncthreads();
            float4 o = ln_row(a.Cbuf, a.gf2, a.betaf2, vb, t, red);
            o.x = fmaxf(o.x, 0.f); o.y = fmaxf(o.y, 0.f);
            o.z = fmaxf(o.z, 0.f); o.w = fmaxf(o.w, 0.f);
            int b = vb >> 4, pp = vb & 15;
#pragma unroll
            for (int q = 0; q < 16; q++) {
                float4 q0 = ((const float4*)(a.qe + (size_t)q * 2048))[t];
                float4 q1 = ((const float4*)(a.qe + (size_t)q * 2048 + 1024))[t];
                size_t orow = ((size_t)(pp * 16 + q) * 64 + b) * 1024;
                ((float4*)(out0 + orow))[t] =
                    make_float4(o.x + q0.x, o.y + q0.y, o.z + q0.z, o.w + q0.w);
                ((float4*)(out1 + orow))[t] =
                    make_float4(o.x + q1.x, o.y + q1.y, o.z + q1.z, o.w + q1.w);
            }
        }
    }
}

extern "C" void kernel_launch(void* const* d_in, const int* in_sizes, int n_in,
                              void* d_out, int out_size, void* d_ws, size_t ws_size,
                              hipStream_t stream) {
    char* ws = (char*)d_ws;
    const size_t MB = 1 << 20;
    KArgs a;
    a.x      = (const float*)d_in[0];
    a.lq     = (const float*)d_in[1];
    a.mask   = (const unsigned char*)d_in[2];
    a.qe     = (const float*)d_in[3];
    a.W1     = (const float*)d_in[4];
    a.b1     = (const float*)d_in[5];
    a.W2     = (const float*)d_in[6];
    a.W3     = (const float*)d_in[8];
    a.b3     = (const float*)d_in[9];
    a.Wc     = (const float*)d_in[10];
    a.bc     = (const float*)d_in[11];
    a.gc     = (const float*)d_in[12];
    a.betac  = (const float*)d_in[13];
    a.Wf1    = (const float*)d_in[14];
    a.bf1    = (const float*)d_in[15];
    a.gf1    = (const float*)d_in[16];
    a.betaf1 = (const float*)d_in[17];
    a.Wf2    = (const float*)d_in[18];
    a.bf2    = (const float*)d_in[19];
    a.gf2    = (const float*)d_in[20];
    a.betaf2 = (const float*)d_in[21];
    a.W3t    = (bf16*)(ws + 0 * MB);
    a.Wct    = (bf16*)(ws + 2 * MB);
    a.Wf1t   = (bf16*)(ws + 4 * MB);
    a.Wf2t   = (bf16*)(ws + 8 * MB);
    a.X      = (bf16*)(ws + 10 * MB);
    a.kbuf   = (float*)(ws + 14 * MB);
    a.mbuf   = (float*)(ws + 14 * MB + 256 * 1024);
    a.attb   = (float*)(ws + 14 * MB + 512 * 1024);
    a.pbuf   = (float*)(ws + 15 * MB);
    a.ybuf   = (bf16*)(ws + 17 * MB);
    a.ctxp   = (bf16*)(ws + 19 * MB);
    a.Cbuf   = (float*)(ws + 21 * MB);     // 4 MB
    a.t1     = (bf16*)(ws + 25 * MB);
    a.kpartial = a.Cbuf;                   // consumed before Cbuf first written
    a.out    = (float*)d_out;

    int maxb = 0;
    hipOccupancyMaxActiveBlocksPerMultiprocessor(&maxb, (const void*)mega_kernel, 256, 0);
    int nb = maxb * 256;
    if (nb > 1024) nb = 1024;
    if (nb < 256) nb = 256;
    void* params[] = { (void*)&a };
    hipLaunchCooperativeKernel((const void*)mega_kernel, dim3(nb), dim3(256),
                               params, 0, stream);
}

// Round 5
// 257.667 us; speedup vs baseline: 3.6613x; 3.6613x over previous
//
#include <hip/hip_runtime.h>

typedef __bf16 bf16;
typedef __bf16 bf16x8 __attribute__((ext_vector_type(8)));
typedef __bf16 bf16x4 __attribute__((ext_vector_type(4)));
typedef float f32x4 __attribute__((ext_vector_type(4)));

#define LCTX 512
#define HD 1024

__device__ __forceinline__ float wave_sum(float v) {
    for (int off = 32; off; off >>= 1) v += __shfl_xor(v, off, 64);
    return v;
}
__device__ __forceinline__ float wave_max(float v) {
    for (int off = 32; off; off >>= 1) v = fmaxf(v, __shfl_xor(v, off, 64));
    return v;
}

// ---------------- prep: 4 weight transposes + lqconv + kpart, one launch ----
// blocks [0,5120): transpose; [5120,6144): lqconv; [6144,6400): kpart
__global__ __launch_bounds__(256) void prep_kernel(const float* __restrict__ W3,
                                                   const float* __restrict__ Wc,
                                                   const float* __restrict__ Wf1,
                                                   const float* __restrict__ Wf2,
                                                   const float* __restrict__ lq,
                                                   const float* __restrict__ x,
                                                   const float* __restrict__ W1,
                                                   bf16* __restrict__ W3t, bf16* __restrict__ Wct,
                                                   bf16* __restrict__ Wf1t, bf16* __restrict__ Wf2t,
                                                   bf16* __restrict__ X,
                                                   float* __restrict__ kpartial) {
    __shared__ __align__(16) char smem[33792];
    int blk = blockIdx.x, t = threadIdx.x;
    if (blk < 5120) {
        float (*tile)[33] = (float(*)[33])smem;
        const float* W; bf16* Wt; int K, N, i;
        if (blk < 1024)      { W = W3;  Wt = W3t;  K = 1024; N = 1024; i = blk; }
        else if (blk < 2048) { W = Wc;  Wt = Wct;  K = 1024; N = 1024; i = blk - 1024; }
        else if (blk < 3072) { W = Wf2; Wt = Wf2t; K = 1024; N = 1024; i = blk - 2048; }
        else                 { W = Wf1; Wt = Wf1t; K = 2048; N = 1024; i = blk - 3072; }
        int k0 = (i >> 5) * 32, n0 = (i & 31) * 32;
        int c = t & 31, r = t >> 5;
#pragma unroll
        for (int j = 0; j < 4; j++)
            tile[r + j * 8][c] = W[(size_t)(k0 + r + j * 8) * N + n0 + c];
        __syncthreads();
#pragma unroll
        for (int j = 0; j < 4; j++)
            Wt[(size_t)(n0 + r + j * 8) * K + k0 + c] = (bf16)tile[c][r + j * 8];
    } else if (blk < 6144) {
        int i = (blk - 5120) * 256 + t;    // over 262144 float4s
        float4 v = ((const float4*)lq)[i];
        int row = i >> 8, h4 = i & 255;
        bf16x4 o = {(bf16)v.x, (bf16)v.y, (bf16)v.z, (bf16)v.w};
        *(bf16x4*)(X + (size_t)row * 2048 + 1024 + h4 * 4) = o;
    } else {
        // kpart: K-split f32 GEMM  M=64(batch) N=1024 K=1024, token-0 rows
        float (*xs)[68] = (float(*)[68])smem;
        float (*wsm)[64] = (float(*)[64])(smem + 17408);
        int kv = blk - 6144;                    // 0..255
        int n0 = (kv & 15) * 64, k0 = (kv >> 4) * 64;
#pragma unroll
        for (int i = 0; i < 4; i++) {
            int f = t + i * 256;
            int b = f >> 4, c = f & 15;
            *(float4*)&xs[b][c * 4] =
                *(const float4*)(x + (size_t)b * LCTX * HD + k0 + c * 4);
        }
#pragma unroll
        for (int i = 0; i < 4; i++) {
            int f = t + i * 256;
            int r = f >> 4, c = f & 15;
            *(float4*)&wsm[r][c * 4] =
                *(const float4*)(W1 + (size_t)(k0 + r) * 1024 + n0 + c * 4);
        }
        __syncthreads();
        int tb = t >> 4, tc = t & 15;
        int b0 = tb * 4;
        float acc[4][4] = {};
        for (int kk = 0; kk < 64; kk += 4) {
            float4 w0 = *(const float4*)&wsm[kk + 0][tc * 4];
            float4 w1 = *(const float4*)&wsm[kk + 1][tc * 4];
            float4 w2 = *(const float4*)&wsm[kk + 2][tc * 4];
            float4 w3 = *(const float4*)&wsm[kk + 3][tc * 4];
            float4 xv[4];
#pragma unroll
            for (int bi = 0; bi < 4; bi++) xv[bi] = *(const float4*)&xs[b0 + bi][kk];
#pragma unroll
            for (int bi = 0; bi < 4; bi++) {
                acc[bi][0] += xv[bi].x * w0.x + xv[bi].y * w1.x + xv[bi].z * w2.x + xv[bi].w * w3.x;
                acc[bi][1] += xv[bi].x * w0.y + xv[bi].y * w1.y + xv[bi].z * w2.y + xv[bi].w * w3.y;
                acc[bi][2] += xv[bi].x * w0.z + xv[bi].y * w1.z + xv[bi].z * w2.z + xv[bi].w * w3.z;
                acc[bi][3] += xv[bi].x * w0.w + xv[bi].y * w1.w + xv[bi].z * w2.w + xv[bi].w * w3.w;
            }
        }
        float* pout = kpartial + ((size_t)(kv >> 4) * 64 + b0) * 1024 + n0 + tc * 4;
#pragma unroll
        for (int bi = 0; bi < 4; bi++)
            *(float4*)(pout + (size_t)bi * 1024) =
                make_float4(acc[bi][0], acc[bi][1], acc[bi][2], acc[bi][3]);
    }
}

// ---------------- mmat (+inline kreduce): m[b,i] = W2[i,:] . k[b,:] ---------
__global__ __launch_bounds__(256) void mmat_kernel(const float* __restrict__ partial,
                                                   const float* __restrict__ b1,
                                                   const float* __restrict__ W2,
                                                   float* __restrict__ mout) {
    __shared__ float ks[1024];
    int b = blockIdx.x, i0 = blockIdx.y * 64, t = threadIdx.x;
    {
        float4 acc = ((const float4*)b1)[t];
#pragma unroll
        for (int kt = 0; kt < 16; kt++) {
            float4 v = ((const float4*)(partial + ((size_t)kt * 64 + b) * 1024))[t];
            acc.x += v.x; acc.y += v.y; acc.z += v.z; acc.w += v.w;
        }
        *(float4*)&ks[t * 4] = acc;
    }
    __syncthreads();
    int wave = t >> 6, lane = t & 63;
    for (int rr = 0; rr < 16; rr++) {
        int i = i0 + wave * 16 + rr;
        const float* wrow = W2 + (size_t)i * 1024;
        float s = 0.f;
#pragma unroll
        for (int j = 0; j < 4; j++) {
            float4 wv = ((const float4*)wrow)[lane + j * 64];
            const float4 kv = *(const float4*)&ks[(lane + j * 64) * 4];
            s += wv.x * kv.x + wv.y * kv.y + wv.z * kv.z + wv.w * kv.w;
        }
        s = wave_sum(s);
        if (lane == 0) mout[(size_t)b * 1024 + i] = s;
    }
}

// ---------------- att[b,l] = x[b,l,:] . m[b,:] ------------------------------
__global__ __launch_bounds__(256) void att_kernel(const float* __restrict__ x,
                                                  const float* __restrict__ m,
                                                  float* __restrict__ att) {
    __shared__ float ms[1024];
    int b = blockIdx.x, l0 = blockIdx.y * 32, t = threadIdx.x;
    *(float4*)&ms[t * 4] = ((const float4*)(m + (size_t)b * 1024))[t];
    __syncthreads();
    int wave = t >> 6, lane = t & 63;
    for (int rr = 0; rr < 8; rr++) {
        int l = l0 + wave * 8 + rr;
        const float* xr = x + ((size_t)b * LCTX + l) * HD;
        float s = 0.f;
#pragma unroll
        for (int j = 0; j < 4; j++) {
            float4 xv = ((const float4*)xr)[lane + j * 64];
            const float4 mv = *(const float4*)&ms[(lane + j * 64) * 4];
            s += xv.x * mv.x + xv.y * mv.y + xv.z * mv.z + xv.w * mv.w;
        }
        s = wave_sum(s);
        if (lane == 0) att[(size_t)b * LCTX + l] = s;
    }
}

// ---------------- fused softmax + y: y[b,pp,c] = sum_l p[b,pp,l]*x[b,l,c] ---
// grid (64, 4): block = (batch b, column chunk c0)
__global__ __launch_bounds__(256) void ysm_kernel(const float* __restrict__ att,
                                                  const unsigned char* __restrict__ mask,
                                                  const float* __restrict__ x,
                                                  bf16* __restrict__ y) {
    __shared__ float ps[16][512];
    __shared__ float att_s[512];
    __shared__ int sstr;
    int b = blockIdx.x, c0 = blockIdx.y * 256, t = threadIdx.x;
    int wave = t >> 6, lane = t & 63;
    // stage att row + mask dtype detect
    if (t == 0) sstr = 4;
    if (t < 128) ((float4*)att_s)[t] = ((const float4*)(att + (size_t)b * LCTX))[t];
    __syncthreads();
    if (t < 128 && ((const unsigned int*)mask)[t] > 1u) sstr = 1;
    __syncthreads();
    int stride = sstr;
    // each wave computes softmax for pp = wave*4 .. wave*4+3 (wave-local reduce)
#pragma unroll
    for (int q = 0; q < 4; q++) {
        int pp = wave * 4 + q;
        size_t mbase = ((size_t)(b * 16 + pp)) * LCTX;
        float av[8];
#pragma unroll
        for (int j = 0; j < 8; j++) {
            int l = lane + j * 64;
            bool mk = mask[(mbase + l) * (size_t)stride] != 0;
            av[j] = mk ? -1e30f : att_s[l];
        }
        float mx = av[0];
#pragma unroll
        for (int j = 1; j < 8; j++) mx = fmaxf(mx, av[j]);
        mx = wave_max(mx);
        float s = 0.f;
#pragma unroll
        for (int j = 0; j < 8; j++) {
            av[j] = (av[j] <= -1e29f) ? 0.f : expf(av[j] - mx);
            s += av[j];
        }
        s = wave_sum(s);
        float inv = 1.f / s;
#pragma unroll
        for (int j = 0; j < 8; j++) ps[pp][lane + j * 64] = av[j] * inv;
    }
    __syncthreads();
    // y accumulation over l
    float acc[16] = {};
    const float* xb = x + (size_t)b * LCTX * HD + c0 + t;
    for (int l = 0; l < 512; l++) {
        float xv = xb[(size_t)l * HD];
#pragma unroll
        for (int q = 0; q < 16; q++) acc[q] += ps[q][l] * xv;
    }
#pragma unroll
    for (int q = 0; q < 16; q++)
        y[((size_t)(b * 16 + q)) * HD + c0 + t] = (bf16)acc[q];
}

// ---------------- MFMA GEMM: 64x64 tile, BK=64, gload_lds + XOR swizzle -----
__device__ __forceinline__ void gl16(const bf16* g, bf16* l) {
    __builtin_amdgcn_global_load_lds((const __attribute__((address_space(1))) void*)g,
                                     (__attribute__((address_space(3))) void*)l, 16, 0, 0);
}
__device__ __forceinline__ bf16x8 ldsfrag(const bf16* base, int row, int kb) {
    return *(const bf16x8*)(base + row * 64 + ((kb ^ (row & 7)) << 3));
}

template <bool OUT_BF16>
__global__ __launch_bounds__(256) void gemm_kernel(const bf16* __restrict__ A, int lda,
                                                   const bf16* __restrict__ Bt, int ldb,
                                                   const float* __restrict__ bias,
                                                   void* __restrict__ Cv, int ldc, int K) {
    __shared__ bf16 sA[2][4096];
    __shared__ bf16 sB[2][4096];
    int tid = threadIdx.x;
    int wave = tid >> 6, lane = tid & 63;
    int m0 = blockIdx.x * 64, n0 = blockIdx.y * 64;
    int wr = (wave >> 1) * 32, wc = (wave & 1) * 32;
    int l16 = lane & 15, lhi = lane >> 4;
    int r0 = tid >> 3, kb = tid & 7;
    int r1 = r0 + 32;
    int sk0 = (kb ^ (r0 & 7)) << 3;
    int sk1 = (kb ^ (r1 & 7)) << 3;
    const bf16* A0 = A + (size_t)(m0 + r0) * lda + sk0;
    const bf16* A1 = A + (size_t)(m0 + r1) * lda + sk1;
    const bf16* B0 = Bt + (size_t)(n0 + r0) * ldb + sk0;
    const bf16* B1 = Bt + (size_t)(n0 + r1) * ldb + sk1;
    int wb0 = (wave * 64) * 8;
    int wb1 = (256 + wave * 64) * 8;

    f32x4 acc00 = {}, acc01 = {}, acc10 = {}, acc11 = {};

    int nt = K >> 6;
    gl16(A0, &sA[0][wb0]); gl16(A1, &sA[0][wb1]);
    gl16(B0, &sB[0][wb0]); gl16(B1, &sB[0][wb1]);
    asm volatile("s_waitcnt vmcnt(0)" ::: "memory");
    __syncthreads();
    int cur = 0;
    for (int tI = 0; tI < nt; ++tI) {
        if (tI + 1 < nt) {
            int ko = (tI + 1) << 6;
            gl16(A0 + ko, &sA[cur ^ 1][wb0]); gl16(A1 + ko, &sA[cur ^ 1][wb1]);
            gl16(B0 + ko, &sB[cur ^ 1][wb0]); gl16(B1 + ko, &sB[cur ^ 1][wb1]);
        }
        const bf16* a = sA[cur];
        const bf16* bt = sB[cur];
#pragma unroll
        for (int ks = 0; ks < 2; ks++) {
            int kbb = ks * 4 + lhi;
            bf16x8 a0 = ldsfrag(a, wr + l16, kbb);
            bf16x8 a1v = ldsfrag(a, wr + 16 + l16, kbb);
            bf16x8 b0v = ldsfrag(bt, wc + l16, kbb);
            bf16x8 b1v = ldsfrag(bt, wc + 16 + l16, kbb);
            acc00 = __builtin_amdgcn_mfma_f32_16x16x32_bf16(a0, b0v, acc00, 0, 0, 0);
            acc01 = __builtin_amdgcn_mfma_f32_16x16x32_bf16(a0, b1v, acc01, 0, 0, 0);
            acc10 = __builtin_amdgcn_mfma_f32_16x16x32_bf16(a1v, b0v, acc10, 0, 0, 0);
            acc11 = __builtin_amdgcn_mfma_f32_16x16x32_bf16(a1v, b1v, acc11, 0, 0, 0);
        }
        asm volatile("s_waitcnt vmcnt(0)" ::: "memory");
        __syncthreads();
        cur ^= 1;
    }
    f32x4 accs[2][2] = {{acc00, acc01}, {acc10, acc11}};
#pragma unroll
    for (int mi = 0; mi < 2; mi++)
#pragma unroll
        for (int ni = 0; ni < 2; ni++)
#pragma unroll
            for (int r = 0; r < 4; r++) {
                int row = m0 + wr + mi * 16 + lhi * 4 + r;
                int col = n0 + wc + ni * 16 + l16;
                float v = accs[mi][ni][r] + bias[col];
                if (OUT_BF16)
                    ((bf16*)Cv)[(size_t)row * ldc + col] = (bf16)v;
                else
                    ((float*)Cv)[(size_t)row * ldc + col] = v;
            }
}

// ---------------- LayerNorm epilogues (modes 0,1) ---------------------------
template <int MODE>
__global__ __launch_bounds__(256) void ln_kernel(const float* __restrict__ C,
                                                 const float* __restrict__ g,
                                                 const float* __restrict__ beta,
                                                 const float* __restrict__ resid,
                                                 void* __restrict__ out) {
    __shared__ float r1[8], r2[8];
    int row = blockIdx.x, t = threadIdx.x;
    float4 v = ((const float4*)(C + (size_t)row * 1024))[t];
    float s = v.x + v.y + v.z + v.w;
    float s2 = v.x * v.x + v.y * v.y + v.z * v.z + v.w * v.w;
    s = wave_sum(s); s2 = wave_sum(s2);
    int wave = t >> 6, lane = t & 63;
    if (lane == 0) { r1[wave] = s; r2[wave] = s2; }
    __syncthreads();
    float S = r1[0] + r1[1] + r1[2] + r1[3];
    float S2 = r2[0] + r2[1] + r2[2] + r2[3];
    float mean = S * (1.f / 1024.f);
    float var = S2 * (1.f / 1024.f) - mean * mean;
    float inv = rsqrtf(var + 1e-5f);
    float4 gv = ((const float4*)g)[t];
    float4 bv = ((const float4*)beta)[t];
    float o[4];
    o[0] = (v.x - mean) * inv * gv.x + bv.x;
    o[1] = (v.y - mean) * inv * gv.y + bv.y;
    o[2] = (v.z - mean) * inv * gv.z + bv.z;
    o[3] = (v.w - mean) * inv * gv.w + bv.w;
    if (MODE == 0) {
        int b = row >> 4;
        const float* x0 = resid + (size_t)b * LCTX * HD + t * 4;
        bf16x4 w = {(bf16)(o[0] + x0[0]), (bf16)(o[1] + x0[1]),
                    (bf16)(o[2] + x0[2]), (bf16)(o[3] + x0[3])};
        *(bf16x4*)((bf16*)out + (size_t)row * 2048 + t * 4) = w;
    } else {
        bf16x4 w = {(bf16)fmaxf(o[0], 0.f), (bf16)fmaxf(o[1], 0.f),
                    (bf16)fmaxf(o[2], 0.f), (bf16)fmaxf(o[3], 0.f)};
        *(bf16x4*)((bf16*)out + (size_t)row * 1024 + t * 4) = w;
    }
}

// ---------------- fused LN(relu) + tile + query_embed + final write ---------
__global__ __launch_bounds__(256) void lnout_kernel(const float* __restrict__ C,
                                                    const float* __restrict__ g,
                                                    const float* __restrict__ beta,
                                                    const float* __restrict__ qe,
                                                    float* __restrict__ out) {
    __shared__ float r1[8], r2[8];
    int row = blockIdx.x, t = threadIdx.x;
    int b = row >> 4, pp = row & 15;
    float4 v = ((const float4*)(C + (size_t)row * 1024))[t];
    float s = v.x + v.y + v.z + v.w;
    float s2 = v.x * v.x + v.y * v.y + v.z * v.z + v.w * v.w;
    s = wave_sum(s); s2 = wave_sum(s2);
    int wave = t >> 6, lane = t & 63;
    if (lane == 0) { r1[wave] = s; r2[wave] = s2; }
    __syncthreads();
    float S = r1[0] + r1[1] + r1[2] + r1[3];
    float S2 = r2[0] + r2[1] + r2[2] + r2[3];
    float mean = S * (1.f / 1024.f);
    float var = S2 * (1.f / 1024.f) - mean * mean;
    float inv = rsqrtf(var + 1e-5f);
    float4 gv = ((const float4*)g)[t];
    float4 bv = ((const float4*)beta)[t];
    float4 ov;
    ov.x = fmaxf((v.x - mean) * inv * gv.x + bv.x, 0.f);
    ov.y = fmaxf((v.y - mean) * inv * gv.y + bv.y, 0.f);
    ov.z = fmaxf((v.z - mean) * inv * gv.z + bv.z, 0.f);
    ov.w = fmaxf((v.w - mean) * inv * gv.w + bv.w, 0.f);
    float* out0 = out;
    float* out1 = out + (size_t)256 * 64 * 1024;
#pragma unroll
    for (int q = 0; q < 16; q++) {
        float4 q0 = ((const float4*)(qe + (size_t)q * 2048))[t];
        float4 q1 = ((const float4*)(qe + (size_t)q * 2048 + 1024))[t];
        size_t orow = ((size_t)(pp * 16 + q) * 64 + b) * 1024;
        ((float4*)(out0 + orow))[t] =
            make_float4(ov.x + q0.x, ov.y + q0.y, ov.z + q0.z, ov.w + q0.w);
        ((float4*)(out1 + orow))[t] =
            make_float4(ov.x + q1.x, ov.y + q1.y, ov.z + q1.z, ov.w + q1.w);
    }
}

extern "C" void kernel_launch(void* const* d_in, const int* in_sizes, int n_in,
                              void* d_out, int out_size, void* d_ws, size_t ws_size,
                              hipStream_t stream) {
    const float* x      = (const float*)d_in[0];
    const float* lq     = (const float*)d_in[1];
    const unsigned char* mask = (const unsigned char*)d_in[2];
    const float* qe     = (const float*)d_in[3];
    const float* W1     = (const float*)d_in[4];
    const float* b1     = (const float*)d_in[5];
    const float* W2     = (const float*)d_in[6];
    const float* W3     = (const float*)d_in[8];
    const float* b3     = (const float*)d_in[9];
    const float* Wc     = (const float*)d_in[10];
    const float* bc     = (const float*)d_in[11];
    const float* gc     = (const float*)d_in[12];
    const float* betac  = (const float*)d_in[13];
    const float* Wf1    = (const float*)d_in[14];
    const float* bf1    = (const float*)d_in[15];
    const float* gf1    = (const float*)d_in[16];
    const float* betaf1 = (const float*)d_in[17];
    const float* Wf2    = (const float*)d_in[18];
    const float* bf2    = (const float*)d_in[19];
    const float* gf2    = (const float*)d_in[20];
    const float* betaf2 = (const float*)d_in[21];

    char* ws = (char*)d_ws;
    const size_t MB = 1 << 20;
    bf16* W3t   = (bf16*)(ws + 0 * MB);
    bf16* Wct   = (bf16*)(ws + 2 * MB);
    bf16* Wf1t  = (bf16*)(ws + 4 * MB);
    bf16* Wf2t  = (bf16*)(ws + 8 * MB);
    bf16* X     = (bf16*)(ws + 10 * MB);
    float* mbuf = (float*)(ws + 14 * MB + 256 * 1024);
    float* attb = (float*)(ws + 14 * MB + 512 * 1024);
    bf16* ybuf  = (bf16*)(ws + 17 * MB);
    bf16* ctxp  = (bf16*)(ws + 19 * MB);
    float* Cbuf = (float*)(ws + 21 * MB);   // 4 MB
    bf16* t1    = (bf16*)(ws + 25 * MB);
    // kpart partials alias Cbuf: consumed by mmat before first f32 gemm writes Cbuf
    float* kpartial = Cbuf;

    prep_kernel<<<6400, 256, 0, stream>>>(W3, Wc, Wf1, Wf2, lq, x, W1,
                                          W3t, Wct, Wf1t, Wf2t, X, kpartial);
    mmat_kernel<<<dim3(64, 16), 256, 0, stream>>>(kpartial, b1, W2, mbuf);
    att_kernel<<<dim3(64, 16), 256, 0, stream>>>(x, mbuf, attb);
    ysm_kernel<<<dim3(64, 4), 256, 0, stream>>>(attb, mask, x, ybuf);
    gemm_kernel<true><<<dim3(16, 16), 256, 0, stream>>>(ybuf, 1024, W3t, 1024, b3,
                                                        ctxp, 1024, 1024);
    gemm_kernel<false><<<dim3(16, 16), 256, 0, stream>>>(ctxp, 1024, Wct, 1024, bc,
                                                         Cbuf, 1024, 1024);
    ln_kernel<0><<<1024, 256, 0, stream>>>(Cbuf, gc, betac, x, X);
    gemm_kernel<false><<<dim3(16, 16), 256, 0, stream>>>(X, 2048, Wf1t, 2048, bf1,
                                                         Cbuf, 1024, 2048);
    ln_kernel<1><<<1024, 256, 0, stream>>>(Cbuf, gf1, betaf1, nullptr, t1);
    gemm_kernel<false><<<dim3(16, 16), 256, 0, stream>>>(t1, 1024, Wf2t, 1024, bf2,
                                                         Cbuf, 1024, 1024);
    lnout_kernel<<<1024, 256, 0, stream>>>(Cbuf, gf2, betaf2, qe, (float*)d_out);
}

// Round 6
// 241.334 us; speedup vs baseline: 3.9091x; 1.0677x over previous
//
#include <hip/hip_runtime.h>

typedef __bf16 bf16;
typedef __bf16 bf16x8 __attribute__((ext_vector_type(8)));
typedef __bf16 bf16x4 __attribute__((ext_vector_type(4)));
typedef float f32x4 __attribute__((ext_vector_type(4)));

#define LCTX 512
#define HD 1024

__device__ __forceinline__ float wave_sum(float v) {
    for (int off = 32; off; off >>= 1) v += __shfl_xor(v, off, 64);
    return v;
}
__device__ __forceinline__ float wave_max(float v) {
    for (int off = 32; off; off >>= 1) v = fmaxf(v, __shfl_xor(v, off, 64));
    return v;
}

// ---------------- prep: 4 weight transposes + lqconv + kpart, one launch ----
// blocks [0,5120): transpose; [5120,6144): lqconv; [6144,6400): kpart
__global__ __launch_bounds__(256) void prep_kernel(const float* __restrict__ W3,
                                                   const float* __restrict__ Wc,
                                                   const float* __restrict__ Wf1,
                                                   const float* __restrict__ Wf2,
                                                   const float* __restrict__ lq,
                                                   const float* __restrict__ x,
                                                   const float* __restrict__ W1,
                                                   bf16* __restrict__ W3t, bf16* __restrict__ Wct,
                                                   bf16* __restrict__ Wf1t, bf16* __restrict__ Wf2t,
                                                   bf16* __restrict__ X,
                                                   float* __restrict__ kpartial) {
    __shared__ __align__(16) char smem[33792];
    int blk = blockIdx.x, t = threadIdx.x;
    if (blk < 5120) {
        float (*tile)[33] = (float(*)[33])smem;
        const float* W; bf16* Wt; int K, N, i;
        if (blk < 1024)      { W = W3;  Wt = W3t;  K = 1024; N = 1024; i = blk; }
        else if (blk < 2048) { W = Wc;  Wt = Wct;  K = 1024; N = 1024; i = blk - 1024; }
        else if (blk < 3072) { W = Wf2; Wt = Wf2t; K = 1024; N = 1024; i = blk - 2048; }
        else                 { W = Wf1; Wt = Wf1t; K = 2048; N = 1024; i = blk - 3072; }
        int k0 = (i >> 5) * 32, n0 = (i & 31) * 32;
        int c = t & 31, r = t >> 5;
#pragma unroll
        for (int j = 0; j < 4; j++)
            tile[r + j * 8][c] = W[(size_t)(k0 + r + j * 8) * N + n0 + c];
        __syncthreads();
#pragma unroll
        for (int j = 0; j < 4; j++)
            Wt[(size_t)(n0 + r + j * 8) * K + k0 + c] = (bf16)tile[c][r + j * 8];
    } else if (blk < 6144) {
        int i = (blk - 5120) * 256 + t;    // over 262144 float4s
        float4 v = ((const float4*)lq)[i];
        int row = i >> 8, h4 = i & 255;
        bf16x4 o = {(bf16)v.x, (bf16)v.y, (bf16)v.z, (bf16)v.w};
        *(bf16x4*)(X + (size_t)row * 2048 + 1024 + h4 * 4) = o;
    } else {
        // kpart: K-split f32 GEMM  M=64(batch) N=1024 K=1024, token-0 rows
        float (*xs)[68] = (float(*)[68])smem;
        float (*wsm)[64] = (float(*)[64])(smem + 17408);
        int kv = blk - 6144;                    // 0..255
        int n0 = (kv & 15) * 64, k0 = (kv >> 4) * 64;
#pragma unroll
        for (int i = 0; i < 4; i++) {
            int f = t + i * 256;
            int b = f >> 4, c = f & 15;
            *(float4*)&xs[b][c * 4] =
                *(const float4*)(x + (size_t)b * LCTX * HD + k0 + c * 4);
        }
#pragma unroll
        for (int i = 0; i < 4; i++) {
            int f = t + i * 256;
            int r = f >> 4, c = f & 15;
            *(float4*)&wsm[r][c * 4] =
                *(const float4*)(W1 + (size_t)(k0 + r) * 1024 + n0 + c * 4);
        }
        __syncthreads();
        int tb = t >> 4, tc = t & 15;
        int b0 = tb * 4;
        float acc[4][4] = {};
        for (int kk = 0; kk < 64; kk += 4) {
            float4 w0 = *(const float4*)&wsm[kk + 0][tc * 4];
            float4 w1 = *(const float4*)&wsm[kk + 1][tc * 4];
            float4 w2 = *(const float4*)&wsm[kk + 2][tc * 4];
            float4 w3 = *(const float4*)&wsm[kk + 3][tc * 4];
            float4 xv[4];
#pragma unroll
            for (int bi = 0; bi < 4; bi++) xv[bi] = *(const float4*)&xs[b0 + bi][kk];
#pragma unroll
            for (int bi = 0; bi < 4; bi++) {
                acc[bi][0] += xv[bi].x * w0.x + xv[bi].y * w1.x + xv[bi].z * w2.x + xv[bi].w * w3.x;
                acc[bi][1] += xv[bi].x * w0.y + xv[bi].y * w1.y + xv[bi].z * w2.y + xv[bi].w * w3.y;
                acc[bi][2] += xv[bi].x * w0.z + xv[bi].y * w1.z + xv[bi].z * w2.z + xv[bi].w * w3.z;
                acc[bi][3] += xv[bi].x * w0.w + xv[bi].y * w1.w + xv[bi].z * w2.w + xv[bi].w * w3.w;
            }
        }
        float* pout = kpartial + ((size_t)(kv >> 4) * 64 + b0) * 1024 + n0 + tc * 4;
#pragma unroll
        for (int bi = 0; bi < 4; bi++)
            *(float4*)(pout + (size_t)bi * 1024) =
                make_float4(acc[bi][0], acc[bi][1], acc[bi][2], acc[bi][3]);
    }
}

// ---------------- mmat (+inline kreduce): m[b,i] = W2[i,:] . k[b,:] ---------
__global__ __launch_bounds__(256) void mmat_kernel(const float* __restrict__ partial,
                                                   const float* __restrict__ b1,
                                                   const float* __restrict__ W2,
                                                   float* __restrict__ mout) {
    __shared__ float ks[1024];
    int b = blockIdx.x, i0 = blockIdx.y * 64, t = threadIdx.x;
    {
        float4 acc = ((const float4*)b1)[t];
#pragma unroll
        for (int kt = 0; kt < 16; kt++) {
            float4 v = ((const float4*)(partial + ((size_t)kt * 64 + b) * 1024))[t];
            acc.x += v.x; acc.y += v.y; acc.z += v.z; acc.w += v.w;
        }
        *(float4*)&ks[t * 4] = acc;
    }
    __syncthreads();
    int wave = t >> 6, lane = t & 63;
    for (int rr = 0; rr < 16; rr++) {
        int i = i0 + wave * 16 + rr;
        const float* wrow = W2 + (size_t)i * 1024;
        float s = 0.f;
#pragma unroll
        for (int j = 0; j < 4; j++) {
            float4 wv = ((const float4*)wrow)[lane + j * 64];
            const float4 kv = *(const float4*)&ks[(lane + j * 64) * 4];
            s += wv.x * kv.x + wv.y * kv.y + wv.z * kv.z + wv.w * kv.w;
        }
        s = wave_sum(s);
        if (lane == 0) mout[(size_t)b * 1024 + i] = s;
    }
}

// ---------------- att[b,l] = x[b,l,:] . m[b,:] ------------------------------
__global__ __launch_bounds__(256) void att_kernel(const float* __restrict__ x,
                                                  const float* __restrict__ m,
                                                  float* __restrict__ att) {
    __shared__ float ms[1024];
    int b = blockIdx.x, l0 = blockIdx.y * 32, t = threadIdx.x;
    *(float4*)&ms[t * 4] = ((const float4*)(m + (size_t)b * 1024))[t];
    __syncthreads();
    int wave = t >> 6, lane = t & 63;
    for (int rr = 0; rr < 8; rr++) {
        int l = l0 + wave * 8 + rr;
        const float* xr = x + ((size_t)b * LCTX + l) * HD;
        float s = 0.f;
#pragma unroll
        for (int j = 0; j < 4; j++) {
            float4 xv = ((const float4*)xr)[lane + j * 64];
            const float4 mv = *(const float4*)&ms[(lane + j * 64) * 4];
            s += xv.x * mv.x + xv.y * mv.y + xv.z * mv.z + xv.w * mv.w;
        }
        s = wave_sum(s);
        if (lane == 0) att[(size_t)b * LCTX + l] = s;
    }
}

// ---------------- ypart: softmax (recomputed) + partial y over l-quarter ----
// grid (64, 4): (batch b, l-quarter). Each thread owns 4 consecutive cols.
// ypartial[lq][b*16+pp][c] f32
__global__ __launch_bounds__(256) void ypart_kernel(const float* __restrict__ att,
                                                    const unsigned char* __restrict__ mask,
                                                    const float* __restrict__ x,
                                                    float* __restrict__ ypartial) {
    __shared__ float ps[16][128];
    __shared__ float att_s[512];
    __shared__ int sstr;
    int b = blockIdx.x, lqi = blockIdx.y, t = threadIdx.x;
    int l0 = lqi * 128;
    int wave = t >> 6, lane = t & 63;
    if (t == 0) sstr = 4;
    if (t < 128) ((float4*)att_s)[t] = ((const float4*)(att + (size_t)b * LCTX))[t];
    __syncthreads();
    if (t < 128 && ((const unsigned int*)mask)[t] > 1u) sstr = 1;
    __syncthreads();
    int stride = sstr;
    // wave w computes softmax for pp = w*4..w*4+3 over ALL 512 l, stores its slice
#pragma unroll
    for (int q = 0; q < 4; q++) {
        int pp = wave * 4 + q;
        size_t mbase = ((size_t)(b * 16 + pp)) * LCTX;
        float av[8];
#pragma unroll
        for (int j = 0; j < 8; j++) {
            int l = lane + j * 64;
            bool mk = mask[(mbase + l) * (size_t)stride] != 0;
            av[j] = mk ? -1e30f : att_s[l];
        }
        float mx = av[0];
#pragma unroll
        for (int j = 1; j < 8; j++) mx = fmaxf(mx, av[j]);
        mx = wave_max(mx);
        float s = 0.f;
#pragma unroll
        for (int j = 0; j < 8; j++) {
            av[j] = (av[j] <= -1e29f) ? 0.f : expf(av[j] - mx);
            s += av[j];
        }
        s = wave_sum(s);
        float inv = 1.f / s;
#pragma unroll
        for (int j = 0; j < 8; j++) {
            int l = lane + j * 64;
            if (l >= l0 && l < l0 + 128) ps[pp][l - l0] = av[j] * inv;
        }
    }
    __syncthreads();
    // partial y: thread owns cols 4t..4t+3; float4 coalesced x loads
    float4 acc[16];
#pragma unroll
    for (int q = 0; q < 16; q++) acc[q] = make_float4(0.f, 0.f, 0.f, 0.f);
    const float4* xb = (const float4*)(x + ((size_t)b * LCTX + l0) * HD) + t;
    for (int l = 0; l < 128; l++) {
        float4 xv = xb[(size_t)l * 256];
#pragma unroll
        for (int q = 0; q < 16; q++) {
            float pv = ps[q][l];
            acc[q].x += pv * xv.x; acc[q].y += pv * xv.y;
            acc[q].z += pv * xv.z; acc[q].w += pv * xv.w;
        }
    }
    float* yp = ypartial + ((size_t)lqi * 1024 + b * 16) * 1024 + t * 4;
#pragma unroll
    for (int q = 0; q < 16; q++)
        *(float4*)(yp + (size_t)q * 1024) = acc[q];
}

// ---------------- yred: y = bf16( sum_lq ypartial ) -------------------------
__global__ __launch_bounds__(256) void yred_kernel(const float* __restrict__ ypartial,
                                                   bf16* __restrict__ y) {
    int i = blockIdx.x * 256 + threadIdx.x;   // over 262144 float4s of y
    float4 a0 = ((const float4*)ypartial)[i];
    float4 a1 = ((const float4*)(ypartial + (size_t)1 * 1024 * 1024))[i];
    float4 a2 = ((const float4*)(ypartial + (size_t)2 * 1024 * 1024))[i];
    float4 a3 = ((const float4*)(ypartial + (size_t)3 * 1024 * 1024))[i];
    float sx = a0.x + a1.x + a2.x + a3.x;
    float sy = a0.y + a1.y + a2.y + a3.y;
    float sz = a0.z + a1.z + a2.z + a3.z;
    float sw = a0.w + a1.w + a2.w + a3.w;
    bf16x4 o = {(bf16)sx, (bf16)sy, (bf16)sz, (bf16)sw};
    *(bf16x4*)(y + (size_t)i * 4) = o;
}

// ---------------- MFMA GEMM: 64x64 tile, BK=64, gload_lds + XOR swizzle -----
__device__ __forceinline__ void gl16(const bf16* g, bf16* l) {
    __builtin_amdgcn_global_load_lds((const __attribute__((address_space(1))) void*)g,
                                     (__attribute__((address_space(3))) void*)l, 16, 0, 0);
}
__device__ __forceinline__ bf16x8 ldsfrag(const bf16* base, int row, int kb) {
    return *(const bf16x8*)(base + row * 64 + ((kb ^ (row & 7)) << 3));
}

template <bool OUT_BF16>
__global__ __launch_bounds__(256) void gemm_kernel(const bf16* __restrict__ A, int lda,
                                                   const bf16* __restrict__ Bt, int ldb,
                                                   const float* __restrict__ bias,
                                                   void* __restrict__ Cv, int ldc, int K) {
    __shared__ bf16 sA[2][4096];
    __shared__ bf16 sB[2][4096];
    int tid = threadIdx.x;
    int wave = tid >> 6, lane = tid & 63;
    int m0 = blockIdx.x * 64, n0 = blockIdx.y * 64;
    int wr = (wave >> 1) * 32, wc = (wave & 1) * 32;
    int l16 = lane & 15, lhi = lane >> 4;
    int r0 = tid >> 3, kb = tid & 7;
    int r1 = r0 + 32;
    int sk0 = (kb ^ (r0 & 7)) << 3;
    int sk1 = (kb ^ (r1 & 7)) << 3;
    const bf16* A0 = A + (size_t)(m0 + r0) * lda + sk0;
    const bf16* A1 = A + (size_t)(m0 + r1) * lda + sk1;
    const bf16* B0 = Bt + (size_t)(n0 + r0) * ldb + sk0;
    const bf16* B1 = Bt + (size_t)(n0 + r1) * ldb + sk1;
    int wb0 = (wave * 64) * 8;
    int wb1 = (256 + wave * 64) * 8;

    f32x4 acc00 = {}, acc01 = {}, acc10 = {}, acc11 = {};

    int nt = K >> 6;
    gl16(A0, &sA[0][wb0]); gl16(A1, &sA[0][wb1]);
    gl16(B0, &sB[0][wb0]); gl16(B1, &sB[0][wb1]);
    asm volatile("s_waitcnt vmcnt(0)" ::: "memory");
    __syncthreads();
    int cur = 0;
    for (int tI = 0; tI < nt; ++tI) {
        if (tI + 1 < nt) {
            int ko = (tI + 1) << 6;
            gl16(A0 + ko, &sA[cur ^ 1][wb0]); gl16(A1 + ko, &sA[cur ^ 1][wb1]);
            gl16(B0 + ko, &sB[cur ^ 1][wb0]); gl16(B1 + ko, &sB[cur ^ 1][wb1]);
        }
        const bf16* a = sA[cur];
        const bf16* bt = sB[cur];
#pragma unroll
        for (int ks = 0; ks < 2; ks++) {
            int kbb = ks * 4 + lhi;
            bf16x8 a0 = ldsfrag(a, wr + l16, kbb);
            bf16x8 a1v = ldsfrag(a, wr + 16 + l16, kbb);
            bf16x8 b0v = ldsfrag(bt, wc + l16, kbb);
            bf16x8 b1v = ldsfrag(bt, wc + 16 + l16, kbb);
            acc00 = __builtin_amdgcn_mfma_f32_16x16x32_bf16(a0, b0v, acc00, 0, 0, 0);
            acc01 = __builtin_amdgcn_mfma_f32_16x16x32_bf16(a0, b1v, acc01, 0, 0, 0);
            acc10 = __builtin_amdgcn_mfma_f32_16x16x32_bf16(a1v, b0v, acc10, 0, 0, 0);
            acc11 = __builtin_amdgcn_mfma_f32_16x16x32_bf16(a1v, b1v, acc11, 0, 0, 0);
        }
        asm volatile("s_waitcnt vmcnt(0)" ::: "memory");
        __syncthreads();
        cur ^= 1;
    }
    f32x4 accs[2][2] = {{acc00, acc01}, {acc10, acc11}};
#pragma unroll
    for (int mi = 0; mi < 2; mi++)
#pragma unroll
        for (int ni = 0; ni < 2; ni++)
#pragma unroll
            for (int r = 0; r < 4; r++) {
                int row = m0 + wr + mi * 16 + lhi * 4 + r;
                int col = n0 + wc + ni * 16 + l16;
                float v = accs[mi][ni][r] + bias[col];
                if (OUT_BF16)
                    ((bf16*)Cv)[(size_t)row * ldc + col] = (bf16)v;
                else
                    ((float*)Cv)[(size_t)row * ldc + col] = v;
            }
}

// ---------------- LayerNorm epilogues (modes 0,1) ---------------------------
template <int MODE>
__global__ __launch_bounds__(256) void ln_kernel(const float* __restrict__ C,
                                                 const float* __restrict__ g,
                                                 const float* __restrict__ beta,
                                                 const float* __restrict__ resid,
                                                 void* __restrict__ out) {
    __shared__ float r1[8], r2[8];
    int row = blockIdx.x, t = threadIdx.x;
    float4 v = ((const float4*)(C + (size_t)row * 1024))[t];
    float s = v.x + v.y + v.z + v.w;
    float s2 = v.x * v.x + v.y * v.y + v.z * v.z + v.w * v.w;
    s = wave_sum(s); s2 = wave_sum(s2);
    int wave = t >> 6, lane = t & 63;
    if (lane == 0) { r1[wave] = s; r2[wave] = s2; }
    __syncthreads();
    float S = r1[0] + r1[1] + r1[2] + r1[3];
    float S2 = r2[0] + r2[1] + r2[2] + r2[3];
    float mean = S * (1.f / 1024.f);
    float var = S2 * (1.f / 1024.f) - mean * mean;
    float inv = rsqrtf(var + 1e-5f);
    float4 gv = ((const float4*)g)[t];
    float4 bv = ((const float4*)beta)[t];
    float o[4];
    o[0] = (v.x - mean) * inv * gv.x + bv.x;
    o[1] = (v.y - mean) * inv * gv.y + bv.y;
    o[2] = (v.z - mean) * inv * gv.z + bv.z;
    o[3] = (v.w - mean) * inv * gv.w + bv.w;
    if (MODE == 0) {
        int b = row >> 4;
        const float* x0 = resid + (size_t)b * LCTX * HD + t * 4;
        bf16x4 w = {(bf16)(o[0] + x0[0]), (bf16)(o[1] + x0[1]),
                    (bf16)(o[2] + x0[2]), (bf16)(o[3] + x0[3])};
        *(bf16x4*)((bf16*)out + (size_t)row * 2048 + t * 4) = w;
    } else {
        bf16x4 w = {(bf16)fmaxf(o[0], 0.f), (bf16)fmaxf(o[1], 0.f),
                    (bf16)fmaxf(o[2], 0.f), (bf16)fmaxf(o[3], 0.f)};
        *(bf16x4*)((bf16*)out + (size_t)row * 1024 + t * 4) = w;
    }
}

// ---------------- fused LN(relu) + tile + query_embed + final write ---------
__global__ __launch_bounds__(256) void lnout_kernel(const float* __restrict__ C,
                                                    const float* __restrict__ g,
                                                    const float* __restrict__ beta,
                                                    const float* __restrict__ qe,
                                                    float* __restrict__ out) {
    __shared__ float r1[8], r2[8];
    int row = blockIdx.x, t = threadIdx.x;
    int b = row >> 4, pp = row & 15;
    float4 v = ((const float4*)(C + (size_t)row * 1024))[t];
    float s = v.x + v.y + v.z + v.w;
    float s2 = v.x * v.x + v.y * v.y + v.z * v.z + v.w * v.w;
    s = wave_sum(s); s2 = wave_sum(s2);
    int wave = t >> 6, lane = t & 63;
    if (lane == 0) { r1[wave] = s; r2[wave] = s2; }
    __syncthreads();
    float S = r1[0] + r1[1] + r1[2] + r1[3];
    float S2 = r2[0] + r2[1] + r2[2] + r2[3];
    float mean = S * (1.f / 1024.f);
    float var = S2 * (1.f / 1024.f) - mean * mean;
    float inv = rsqrtf(var + 1e-5f);
    float4 gv = ((const float4*)g)[t];
    float4 bv = ((const float4*)beta)[t];
    float4 ov;
    ov.x = fmaxf((v.x - mean) * inv * gv.x + bv.x, 0.f);
    ov.y = fmaxf((v.y - mean) * inv * gv.y + bv.y, 0.f);
    ov.z = fmaxf((v.z - mean) * inv * gv.z + bv.z, 0.f);
    ov.w = fmaxf((v.w - mean) * inv * gv.w + bv.w, 0.f);
    float* out0 = out;
    float* out1 = out + (size_t)256 * 64 * 1024;
#pragma unroll
    for (int q = 0; q < 16; q++) {
        float4 q0 = ((const float4*)(qe + (size_t)q * 2048))[t];
        float4 q1 = ((const float4*)(qe + (size_t)q * 2048 + 1024))[t];
        size_t orow = ((size_t)(pp * 16 + q) * 64 + b) * 1024;
        ((float4*)(out0 + orow))[t] =
            make_float4(ov.x + q0.x, ov.y + q0.y, ov.z + q0.z, ov.w + q0.w);
        ((float4*)(out1 + orow))[t] =
            make_float4(ov.x + q1.x, ov.y + q1.y, ov.z + q1.z, ov.w + q1.w);
    }
}

extern "C" void kernel_launch(void* const* d_in, const int* in_sizes, int n_in,
                              void* d_out, int out_size, void* d_ws, size_t ws_size,
                              hipStream_t stream) {
    const float* x      = (const float*)d_in[0];
    const float* lq     = (const float*)d_in[1];
    const unsigned char* mask = (const unsigned char*)d_in[2];
    const float* qe     = (const float*)d_in[3];
    const float* W1     = (const float*)d_in[4];
    const float* b1     = (const float*)d_in[5];
    const float* W2     = (const float*)d_in[6];
    const float* W3     = (const float*)d_in[8];
    const float* b3     = (const float*)d_in[9];
    const float* Wc     = (const float*)d_in[10];
    const float* bc     = (const float*)d_in[11];
    const float* gc     = (const float*)d_in[12];
    const float* betac  = (const float*)d_in[13];
    const float* Wf1    = (const float*)d_in[14];
    const float* bf1    = (const float*)d_in[15];
    const float* gf1    = (const float*)d_in[16];
    const float* betaf1 = (const float*)d_in[17];
    const float* Wf2    = (const float*)d_in[18];
    const float* bf2    = (const float*)d_in[19];
    const float* gf2    = (const float*)d_in[20];
    const float* betaf2 = (const float*)d_in[21];

    char* ws = (char*)d_ws;
    const size_t MB = 1 << 20;
    bf16* W3t   = (bf16*)(ws + 0 * MB);
    bf16* Wct   = (bf16*)(ws + 2 * MB);
    bf16* Wf1t  = (bf16*)(ws + 4 * MB);
    bf16* Wf2t  = (bf16*)(ws + 8 * MB);
    bf16* X     = (bf16*)(ws + 10 * MB);
    float* mbuf = (float*)(ws + 14 * MB + 256 * 1024);
    float* attb = (float*)(ws + 14 * MB + 512 * 1024);
    bf16* ybuf  = (bf16*)(ws + 17 * MB);
    bf16* ctxp  = (bf16*)(ws + 19 * MB);
    float* Cbuf = (float*)(ws + 21 * MB);   // 4 MB
    bf16* t1    = (bf16*)(ws + 25 * MB);
    float* ypartial = (float*)(ws + 32 * MB);   // 16 MB (ws is ~512 MB)
    // kpart partials alias Cbuf: consumed by mmat before first f32 gemm writes Cbuf
    float* kpartial = Cbuf;

    prep_kernel<<<6400, 256, 0, stream>>>(W3, Wc, Wf1, Wf2, lq, x, W1,
                                          W3t, Wct, Wf1t, Wf2t, X, kpartial);
    mmat_kernel<<<dim3(64, 16), 256, 0, stream>>>(kpartial, b1, W2, mbuf);
    att_kernel<<<dim3(64, 16), 256, 0, stream>>>(x, mbuf, attb);
    ypart_kernel<<<dim3(64, 4), 256, 0, stream>>>(attb, mask, x, ypartial);
    yred_kernel<<<1024, 256, 0, stream>>>(ypartial, ybuf);
    gemm_kernel<true><<<dim3(16, 16), 256, 0, stream>>>(ybuf, 1024, W3t, 1024, b3,
                                                        ctxp, 1024, 1024);
    gemm_kernel<false><<<dim3(16, 16), 256, 0, stream>>>(ctxp, 1024, Wct, 1024, bc,
                                                         Cbuf, 1024, 1024);
    ln_kernel<0><<<1024, 256, 0, stream>>>(Cbuf, gc, betac, x, X);
    gemm_kernel<false><<<dim3(16, 16), 256, 0, stream>>>(X, 2048, Wf1t, 2048, bf1,
                                                         Cbuf, 1024, 2048);
    ln_kernel<1><<<1024, 256, 0, stream>>>(Cbuf, gf1, betaf1, nullptr, t1);
    gemm_kernel<false><<<dim3(16, 16), 256, 0, stream>>>(t1, 1024, Wf2t, 1024, bf2,
                                                         Cbuf, 1024, 1024);
    lnout_kernel<<<1024, 256, 0, stream>>>(Cbuf, gf2, betaf2, qe, (float*)d_out);
}